// Round 12
// baseline (277.428 us; speedup 1.0000x reference)
//
#include <hip/hip_runtime.h>
#include <hip/hip_bf16.h>
#include <cstdint>
#include <cstddef>

// Problem constants (fixed by the reference):
#define HD   1024            // hidden H
#define NK   4               // heads K
#define DD   512             // H/2
#define LSEQ 2048            // L
#define NB   16              // B
#define MTOT (NB*LSEQ)       // 32768 tokens
#define NF2  (NK*DD)         // 2048 fused width (4 heads x 512)

typedef __attribute__((ext_vector_type(4))) float f32x4;
typedef __attribute__((ext_vector_type(8))) short bf16x8;

// async global->LDS, 16B per lane; LDS dest is wave-uniform base + lane*16
#define GLOAD16(gp, lp) __builtin_amdgcn_global_load_lds( \
    (const __attribute__((address_space(1))) void*)(gp),  \
    (__attribute__((address_space(3))) void*)(lp), 16, 0, 0)

static __device__ __forceinline__ ushort f2bf(float f) {
  union { float f; unsigned u; } x; x.f = f;
  unsigned r = x.u + 0x7FFFu + ((x.u >> 16) & 1u);   // RNE
  return (ushort)(r >> 16);
}

// packed f32x2 -> bf16x2 (RNE) -- compiler emits v_cvt_pk_bf16_f32 (m240)
static __device__ __forceinline__ unsigned pkbf(float a, float b) {
  float2 t; t.x = a; t.y = b;
  __hip_bfloat162 h = __float22bfloat162_rn(t);
  return *reinterpret_cast<unsigned*>(&h);
}

static __device__ __forceinline__ float fast_tanh(float x) {
  x = fminf(fmaxf(x, -15.f), 15.f);
  float t = __expf(2.0f * x);
  return (t - 1.0f) / (t + 1.0f);
}

// ---------------------------------------------------------------------------
__global__ void detect_mask_kernel(const unsigned char* __restrict__ m, int nbytes,
                                   int* __restrict__ flag) {
  int found = 0;
  for (int i = blockIdx.x * blockDim.x + threadIdx.x; i < nbytes;
       i += gridDim.x * blockDim.x)
    if ((i & 3) && m[i]) found = 1;
  if (__any(found) && (threadIdx.x & 63) == 0) atomicOr(flag, 1);
}

// WpH[h][c][j] = bf16(Wp[c][h*1024 + j]);  4M elements, 4 per thread
__global__ void cvt_wp_heads_kernel(const float* __restrict__ Wp,
                                    ushort* __restrict__ WpH) {
  long i4 = ((long)blockIdx.x * blockDim.x + threadIdx.x) * 4;  // < 4*1024*1024
  int h = (int)(i4 >> 20);
  int c = (int)((i4 >> 10) & 1023);
  int j = (int)(i4 & 1023);
  f32x4 v = *(const f32x4*)(Wp + (long)c * (NK * HD) + h * HD + j);
  ushort4 o; o.x = f2bf(v.x); o.y = f2bf(v.y); o.z = f2bf(v.z); o.w = f2bf(v.w);
  *(ushort4*)(WpH + i4) = o;
}

// dst[c][r] = bf16(src[r][c]); grid.z = batch
__global__ void transpose_cvt_kernel(const float* __restrict__ src,
                                     ushort* __restrict__ dst,
                                     int R, int C, long sBatch, long dBatch) {
  __shared__ float tile[32][33];
  const float* s = src + blockIdx.z * sBatch;
  ushort* d = dst + blockIdx.z * dBatch;
  int c0 = blockIdx.x * 32, r0 = blockIdx.y * 32;
  int tx = threadIdx.x, ty = threadIdx.y;  // (32, 8)
  #pragma unroll
  for (int i = 0; i < 32; i += 8)
    tile[ty + i][tx] = s[(long)(r0 + ty + i) * C + (c0 + tx)];
  __syncthreads();
  #pragma unroll
  for (int i = 0; i < 32; i += 8)
    d[(long)(c0 + ty + i) * R + (r0 + tx)] = f2bf(tile[tx][ty + i]);
}

// ---------------------------------------------------------------------------
// 128x128 tile, BK=32, 4 waves (2x2 of 64x64), single-buffer LDS, 2-sync loop
// (m97/round-1 structure, proven best-on-this-shape). Supertile XCD map.
// AF32=1: A operand is f32 in global; staged raw via global_load_lds into a
//   16KB f32 LDS tile (16B-chunk XOR swizzle p = c ^ (row&7): 64 lanes hit all
//   8 bank-quads uniformly = b128 floor), converted to bf16 at fragment read
//   via v_cvt_pk_bf16_f32. Eliminates the separate f32->bf16 cvt pass.
// MODE 0: Cout[z*cZs + row*ldc + col] = bf16(acc)
// MODE 1: partial[(col>>6)][m0glob+row] = wave's 64-col sum of tanh(acc+b1)*W2
template<int MODE, int AF32>
__global__ __launch_bounds__(256, 2)
void gemm128_kernel(const void* __restrict__ A, int lda, long aZs,
                    const ushort* __restrict__ Bt, int ldb, long bZs, int Kdim,
                    ushort* __restrict__ Cout, int ldc, long cZs,
                    const float* __restrict__ b1, const float* __restrict__ W2,
                    float* __restrict__ partialOut, int m0glob) {
  // AF32: A f32 [0,16384), B bf16 [16384,24576). else: A [0,8192) B [8192,16384)
  __shared__ __align__(16) char lds[AF32 ? 24576 : 16384];
  constexpr int AB = AF32 ? 16384 : 8192;   // B region base

  const int tid = threadIdx.x;
  const int wave = tid >> 6, lane = tid & 63;
  const int z = blockIdx.z;

  // supertile XCD mapping (bijective when nMB%8==0); else column-major
  const int bid = blockIdx.x + gridDim.x * blockIdx.y;
  const int nMB = gridDim.x, nNB = gridDim.y;
  int m0, n0;
  if ((nMB & 7) == 0) {
    const int x = bid & 7, j = bid >> 3;
    m0 = (x * (nMB >> 3) + j / nNB) * 128;
    n0 = (j % nNB) * 128;
  } else {
    m0 = (bid % nMB) * 128; n0 = (bid / nMB) * 128;
  }

  const float*  Agf = (const float*)A  + z * aZs + (long)m0 * lda;
  const ushort* Agb = (const ushort*)A + z * aZs + (long)m0 * lda;
  const ushort* Bg  = Bt + z * bZs + (long)n0 * ldb;

  // wave tile: wr in {0,1} -> 64 M-rows; wc in {0,1} -> 64 N-cols
  const int wr = wave >> 1, wc = wave & 1;
  const int rsel = lane & 15, ch = lane >> 4;

  // --- B read (bf16, 64B rows, chunk XOR (row>>1)&3) ---
  const int chunkC = (ch ^ ((rsel >> 1) & 3)) << 4;
  const int laneB = AB + wc * 4096 + rsel * 64 + chunkC;     // + nf*1024
  // --- A read ---
  // AF32: f32 rows 128B; frag = two b128 at 16B-chunks (2ch)^s, (2ch+1)^s
  const int sA = rsel & 7;
  const int laneA0 = (wr * 64 + rsel) * 128 + (((ch * 2)     ^ sA) << 4); // + mf*2048
  const int laneA1 = (wr * 64 + rsel) * 128 + (((ch * 2 + 1) ^ sA) << 4);
  // !AF32: bf16 like B
  const int laneAb = wr * 4096 + rsel * 64 + chunkC;         // + mf*1024

  // --- staging maps (linear LDS dest, inverse-swizzled global src) ---
  // A f32: issue i in 0..3: row = i*32 + wave*8 + lane/8, chunk16 = lane&7
  const int stRowA = wave * 8 + (lane >> 3);
  const int cSrcA = (((lane & 7) ^ ((lane >> 3) & 7))) * 4;  // f32 elems
  // bf16 (B always; A when !AF32): issue i in 0..1: row = i*64 + wave*16 + lane/4
  const int stRowB = wave * 16 + (lane >> 2);
  const int stCg = ((lane & 3) ^ ((lane >> 3) & 3)) * 8;     // bf16 elems

  f32x4 acc[4][4] = {};

  const int ksteps = Kdim >> 5;
  for (int kt = 0; kt < ksteps; ++kt) {
    if constexpr (AF32) {
      const int kk32 = (kt << 5) + cSrcA;
      #pragma unroll
      for (int i = 0; i < 4; ++i)
        GLOAD16(Agf + (long)(i * 32 + stRowA) * lda + kk32,
                (char*)lds + i * 4096 + wave * 1024);
      const int kkb = (kt << 5) + stCg;
      GLOAD16(Bg + (long)stRowB * ldb + kkb,        (char*)lds + AB + wave * 1024);
      GLOAD16(Bg + (long)(64 + stRowB) * ldb + kkb, (char*)lds + AB + 4096 + wave * 1024);
    } else {
      const int kk = (kt << 5) + stCg;
      GLOAD16(Agb + (long)stRowB * lda + kk,        (char*)lds + wave * 1024);
      GLOAD16(Agb + (long)(64 + stRowB) * lda + kk, (char*)lds + 4096 + wave * 1024);
      GLOAD16(Bg + (long)stRowB * ldb + kk,         (char*)lds + AB + wave * 1024);
      GLOAD16(Bg + (long)(64 + stRowB) * ldb + kk,  (char*)lds + AB + 4096 + wave * 1024);
    }
    __syncthreads();  // drains vmcnt -> staged data visible

    bf16x8 aF[4], bF[4];
    if constexpr (AF32) {
      #pragma unroll
      for (int mf = 0; mf < 4; ++mf) {
        f32x4 va = *(const f32x4*)(lds + laneA0 + mf * 2048);
        f32x4 vb = *(const f32x4*)(lds + laneA1 + mf * 2048);
        unsigned* ap = (unsigned*)&aF[mf];
        ap[0] = pkbf(va[0], va[1]); ap[1] = pkbf(va[2], va[3]);
        ap[2] = pkbf(vb[0], vb[1]); ap[3] = pkbf(vb[2], vb[3]);
      }
    } else {
      #pragma unroll
      for (int mf = 0; mf < 4; ++mf)
        aF[mf] = *(const bf16x8*)(lds + laneAb + mf * 1024);
    }
    #pragma unroll
    for (int nf = 0; nf < 4; ++nf)
      bF[nf] = *(const bf16x8*)(lds + laneB + nf * 1024);
    #pragma unroll
    for (int mf = 0; mf < 4; ++mf)
      #pragma unroll
      for (int nf = 0; nf < 4; ++nf)
        acc[mf][nf] = __builtin_amdgcn_mfma_f32_16x16x32_bf16(
            aF[mf], bF[nf], acc[mf][nf], 0, 0, 0);
    __syncthreads();  // all reads done before next stage overwrites
  }

  if constexpr (MODE == 0) {
    #pragma unroll
    for (int mf = 0; mf < 4; ++mf)
      #pragma unroll
      for (int nf = 0; nf < 4; ++nf) {
        const int col = n0 + wc * 64 + nf * 16 + (lane & 15);
        #pragma unroll
        for (int r = 0; r < 4; ++r) {
          const int row = m0 + wr * 64 + mf * 16 + ((lane >> 4) << 2) + r;
          Cout[z * cZs + (long)row * ldc + col] = f2bf(acc[mf][nf][r]);
        }
      }
  } else {
    float b1v[4], w2v[4];
    #pragma unroll
    for (int nf = 0; nf < 4; ++nf) {
      const int col = n0 + wc * 64 + nf * 16 + (lane & 15);
      b1v[nf] = b1[col];
      w2v[nf] = W2[col];
    }
    // wslice = (first col of this wave)/64 ; disjoint across waves/blocks
    const int wslice = (n0 + wc * 64) >> 6;
    float* pb = partialOut + (long)wslice * MTOT + m0glob + m0 + wr * 64;
    #pragma unroll
    for (int mf = 0; mf < 4; ++mf)
      #pragma unroll
      for (int r = 0; r < 4; ++r) {
        float s = 0.f;
        #pragma unroll
        for (int nf = 0; nf < 4; ++nf)
          s += fast_tanh(acc[mf][nf][r] + b1v[nf]) * w2v[nf];
        s += __shfl_xor(s, 1, 64);
        s += __shfl_xor(s, 2, 64);
        s += __shfl_xor(s, 4, 64);
        s += __shfl_xor(s, 8, 64);
        if ((lane & 15) == 0)
          pb[mf * 16 + ((lane >> 4) << 2) + r] = s;   // plain store, no atomic
      }
  }
}

// ---------------------------------------------------------------------------
// masked softmax over L per (k,b) row; sums 8 col-slices per head first.
// partial: [32][MTOT] f32, wslice ws covers cols ws*64..ws*64+63; head = ws>>3.
__global__ __launch_bounds__(256)
void masked_softmax_kernel(const float* __restrict__ partial,
                           const unsigned char* __restrict__ maskB,
                           const int* __restrict__ maskI,
                           const int* __restrict__ flag,
                           float* __restrict__ out) {
  const int kb = blockIdx.x;          // k*NB + b
  const int k = kb >> 4, b = kb & (NB - 1);
  const long base = (long)kb * LSEQ;
  const bool isByte = (*flag != 0);
  const int tid = threadIdx.x;
  const float* pk = partial + (long)(k * 8) * MTOT + (long)b * LSEQ;

  float x[8];
  float mx = -3.0e38f;
  #pragma unroll
  for (int j = 0; j < 8; ++j) {
    int l = tid + j * 256;
    float v = 0.f;
    #pragma unroll
    for (int ws = 0; ws < 8; ++ws) v += pk[(long)ws * MTOT + l];
    bool msk = isByte ? (maskB[b * LSEQ + l] != 0) : (maskI[b * LSEQ + l] != 0);
    v = msk ? -1e9f : v;
    x[j] = v; mx = fmaxf(mx, v);
  }
  __shared__ float redm[4], reds[4];
  #pragma unroll
  for (int off = 32; off >= 1; off >>= 1) mx = fmaxf(mx, __shfl_xor(mx, off, 64));
  if ((tid & 63) == 0) redm[tid >> 6] = mx;
  __syncthreads();
  mx = fmaxf(fmaxf(redm[0], redm[1]), fmaxf(redm[2], redm[3]));

  float sum = 0.f;
  #pragma unroll
  for (int j = 0; j < 8; ++j) { x[j] = __expf(x[j] - mx); sum += x[j]; }
  #pragma unroll
  for (int off = 32; off >= 1; off >>= 1) sum += __shfl_xor(sum, off, 64);
  if ((tid & 63) == 0) reds[tid >> 6] = sum;
  __syncthreads();
  sum = reds[0] + reds[1] + reds[2] + reds[3];

  float inv = 1.0f / sum;
  #pragma unroll
  for (int j = 0; j < 8; ++j) out[base + tid + j * 256] = x[j] * inv;
}

// ---------------------------------------------------------------------------
extern "C" void kernel_launch(void* const* d_in, const int* in_sizes, int n_in,
                              void* d_out, int out_size, void* d_ws, size_t ws_size,
                              hipStream_t stream) {
  const float* hidden = (const float*)d_in[0];
  const void*  masks  = d_in[1];
  const float* Wp     = (const float*)d_in[2];
  const float* W1     = (const float*)d_in[3];
  const float* b1     = (const float*)d_in[4];
  const float* W2     = (const float*)d_in[5];
  float* out = (float*)d_out;

  // workspace layout (bytes)
  char* ws = (char*)d_ws;
  ushort* W1T      = (ushort*)(ws + 0);                 //  4,194,304  [4][512][1024] bf16
  ushort* WpH      = (ushort*)(ws + 4194304);           //  8,388,608  [4][1024][1024] bf16
  ushort* WfT      = (ushort*)(ws + 12582912);          //  4,194,304  [2048][1024] bf16
  float*  partial  = (float*) (ws + 16777216);          //  4,194,304  [32][32768] f32
  int*    flag     = (int*)   (ws + 20971520);          //        256

  hipMemsetAsync(flag, 0, 256, stream);

  detect_mask_kernel<<<8, 256, 0, stream>>>((const unsigned char*)masks, NB * LSEQ, flag);

  // W1T[h][d][j] = bf16(W1[h][j][d])
  dim3 tb(32, 8);
  transpose_cvt_kernel<<<dim3(DD / 32, HD / 32, NK), tb, 0, stream>>>(
      W1, W1T, HD, DD, (long)HD * DD, (long)DD * HD);
  // WpH[h][c][j] = bf16(Wp[c][h*1024+j])
  cvt_wp_heads_kernel<<<4096, 256, 0, stream>>>(Wp, WpH);

  // WfT[h*512+d][c] = sum_j W1T[h][d][j] * WpH[h][c][j]   (= (Wp@W1)^T per head)
  gemm128_kernel<0, 0><<<dim3(DD / 128, HD / 128, NK), 256, 0, stream>>>(
      W1T, HD, (long)DD * HD,
      WpH, HD, (long)HD * HD, HD,
      WfT, HD, (long)DD * HD,
      nullptr, nullptr, nullptr, 0);

  // fused GEMM straight from f32 hidden (no cvt pass, no chunking):
  // partial[col/64][row] = sum over 64 cols of tanh(hidden@WfT^T + b1)*W2
  gemm128_kernel<1, 1><<<dim3(MTOT / 128, NF2 / 128, 1), 256, 0, stream>>>(
      hidden, HD, 0,
      WfT, HD, 0, HD,
      nullptr, 0, 0,
      b1, W2, partial, 0);

  masked_softmax_kernel<<<NK * NB, 256, 0, stream>>>(
      partial, (const unsigned char*)masks, (const int*)masks, flag, out);
}

// Round 13
// 251.951 us; speedup vs baseline: 1.1011x; 1.1011x over previous
//
#include <hip/hip_runtime.h>
#include <hip/hip_bf16.h>
#include <cstdint>
#include <cstddef>

// Problem constants (fixed by the reference):
#define HD   1024            // hidden H
#define NK   4               // heads K
#define DD   512             // H/2
#define LSEQ 2048            // L
#define NB   16              // B
#define MTOT (NB*LSEQ)       // 32768 tokens
#define NF2  (NK*DD)         // 2048 fused width (4 heads x 512)

typedef __attribute__((ext_vector_type(4))) float f32x4;
typedef __attribute__((ext_vector_type(8))) short bf16x8;

// async global->LDS, 16B per lane; LDS dest is wave-uniform base + lane*16
#define GLOAD16(gp, lp) __builtin_amdgcn_global_load_lds( \
    (const __attribute__((address_space(1))) void*)(gp),  \
    (__attribute__((address_space(3))) void*)(lp), 16, 0, 0)

static __device__ __forceinline__ ushort f2bf(float f) {
  union { float f; unsigned u; } x; x.f = f;
  unsigned r = x.u + 0x7FFFu + ((x.u >> 16) & 1u);   // RNE
  return (ushort)(r >> 16);
}

static __device__ __forceinline__ float fast_tanh(float x) {
  x = fminf(fmaxf(x, -15.f), 15.f);
  float t = __expf(2.0f * x);
  return (t - 1.0f) / (t + 1.0f);
}

// ---------------------------------------------------------------------------
__global__ void detect_mask_kernel(const unsigned char* __restrict__ m, int nbytes,
                                   int* __restrict__ flag) {
  int found = 0;
  for (int i = blockIdx.x * blockDim.x + threadIdx.x; i < nbytes;
       i += gridDim.x * blockDim.x)
    if ((i & 3) && m[i]) found = 1;
  if (__any(found) && (threadIdx.x & 63) == 0) atomicOr(flag, 1);
}

// ---------------------------------------------------------------------------
__global__ void cvt_f32_bf16_kernel(const float* __restrict__ src,
                                    ushort* __restrict__ dst, long n) {
  long stride = (long)gridDim.x * blockDim.x * 4;
  for (long i = ((long)blockIdx.x * blockDim.x + threadIdx.x) * 4; i < n; i += stride) {
    f32x4 v = *(const f32x4*)(src + i);
    ushort4 o; o.x = f2bf(v.x); o.y = f2bf(v.y); o.z = f2bf(v.z); o.w = f2bf(v.w);
    *(ushort4*)(dst + i) = o;
  }
}

// WpH[h][c][j] = bf16(Wp[c][h*1024 + j]);  4M elements, 4 per thread
__global__ void cvt_wp_heads_kernel(const float* __restrict__ Wp,
                                    ushort* __restrict__ WpH) {
  long i4 = ((long)blockIdx.x * blockDim.x + threadIdx.x) * 4;  // < 4*1024*1024
  int h = (int)(i4 >> 20);
  int c = (int)((i4 >> 10) & 1023);
  int j = (int)(i4 & 1023);
  f32x4 v = *(const f32x4*)(Wp + (long)c * (NK * HD) + h * HD + j);
  ushort4 o; o.x = f2bf(v.x); o.y = f2bf(v.y); o.z = f2bf(v.z); o.w = f2bf(v.w);
  *(ushort4*)(WpH + i4) = o;
}

// dst[c][r] = bf16(src[r][c]); grid.z = batch
__global__ void transpose_cvt_kernel(const float* __restrict__ src,
                                     ushort* __restrict__ dst,
                                     int R, int C, long sBatch, long dBatch) {
  __shared__ float tile[32][33];
  const float* s = src + blockIdx.z * sBatch;
  ushort* d = dst + blockIdx.z * dBatch;
  int c0 = blockIdx.x * 32, r0 = blockIdx.y * 32;
  int tx = threadIdx.x, ty = threadIdx.y;  // (32, 8)
  #pragma unroll
  for (int i = 0; i < 32; i += 8)
    tile[ty + i][tx] = s[(long)(r0 + ty + i) * C + (c0 + tx)];
  __syncthreads();
  #pragma unroll
  for (int i = 0; i < 32; i += 8)
    d[(long)(c0 + ty + i) * R + (r0 + tx)] = f2bf(tile[tx][ty + i]);
}

// ---------------------------------------------------------------------------
// 128x128 tile, BK=32, 4 waves (2x2 of 64x64), single-buffer 16KB LDS, 2-sync
// loop (m97 structure — measured best of 7 variants on this shape). SREP:
// each block computes SREP m-tiles at the same n0 (amortizes per-block fixed
// cost: cold-prologue HBM chain, epilogue, teardown; B panel stays hot in L2;
// staging of tile s+1 overlaps register-only epilogue of tile s).
// Supertile XCD map. Chunk-XOR swizzle (0 conflicts).
// A: [M,lda] bf16 row-major (+z*aZs). Bt: [N,ldb] bf16 row-major (+z*bZs).
// MODE 0: Cout[z*cZs + row*ldc + col] = bf16(acc)
// MODE 1: partial[(col>>6)][m0glob+row] = wave's 64-col sum of tanh(acc+b1)*W2
template<int MODE, int SREP>
__global__ __launch_bounds__(256, 2)
void gemm128_kernel(const ushort* __restrict__ A, int lda, long aZs,
                    const ushort* __restrict__ Bt, int ldb, long bZs, int Kdim,
                    ushort* __restrict__ Cout, int ldc, long cZs,
                    const float* __restrict__ b1, const float* __restrict__ W2,
                    float* __restrict__ partialOut, int m0glob) {
  __shared__ __align__(16) char lds[16384];   // A: [0,8192), B: [8192,16384)

  const int tid = threadIdx.x;
  const int wave = tid >> 6, lane = tid & 63;
  const int z = blockIdx.z;
  constexpr int TM = 128 * SREP;

  // supertile XCD mapping (bijective when nMB%8==0); else column-major
  const int bid = blockIdx.x + gridDim.x * blockIdx.y;
  const int nMB = gridDim.x, nNB = gridDim.y;
  int m0, n0;
  if ((nMB & 7) == 0) {
    const int x = bid & 7, j = bid >> 3;
    m0 = (x * (nMB >> 3) + j / nNB) * TM;
    n0 = (j % nNB) * 128;
  } else {
    m0 = (bid % nMB) * TM; n0 = (bid / nMB) * 128;
  }

  const ushort* Bg = Bt + z * bZs + (long)n0 * ldb;

  // wave tile: wr in {0,1} -> 64 M-rows; wc in {0,1} -> 64 N-cols
  const int wr = wave >> 1, wc = wave & 1;
  const int rsel = lane & 15, ch = lane >> 4;
  // read-side swizzle: chunk ^= (row>>1)&3 (lane-constant: frag row bases %8==0)
  const int chunkC = (ch ^ ((rsel >> 1) & 3)) << 4;
  const int laneA = wr * 4096 + rsel * 64 + chunkC;          // + mf*1024
  const int laneB = 8192 + wc * 4096 + rsel * 64 + chunkC;   // + nf*1024

  // staging: per issue i in {0,1}: rows i*64 + wave*16 + lane/4
  // inverse-swizzled global col chunk; linear LDS dest
  const int stRow = wave * 16 + (lane >> 2);                  // + i*64
  const int stCg = ((lane & 3) ^ ((lane >> 3) & 3)) * 8;      // global col elems
  const int ldsOff = wave * 1024;                             // + i*4096

  // MODE1 epilogue constants (col-dependent only; hoisted out of s-loop)
  float b1v[4], w2v[4];
  if constexpr (MODE == 1) {
    #pragma unroll
    for (int nf = 0; nf < 4; ++nf) {
      const int col = n0 + wc * 64 + nf * 16 + (lane & 15);
      b1v[nf] = b1[col];
      w2v[nf] = W2[col];
    }
  }

  const int ksteps = Kdim >> 5;
  #pragma unroll
  for (int s = 0; s < SREP; ++s) {
    const ushort* Ag = A + z * aZs + (long)(m0 + s * 128) * lda;
    f32x4 acc[4][4] = {};

    for (int kt = 0; kt < ksteps; ++kt) {
      const int kk = (kt << 5) + stCg;
      GLOAD16(Ag + (long)stRow * lda + kk,        (char*)lds + ldsOff);
      GLOAD16(Ag + (long)(64 + stRow) * lda + kk, (char*)lds + 4096 + ldsOff);
      GLOAD16(Bg + (long)stRow * ldb + kk,        (char*)lds + 8192 + ldsOff);
      GLOAD16(Bg + (long)(64 + stRow) * ldb + kk, (char*)lds + 12288 + ldsOff);
      __syncthreads();  // drains vmcnt -> staged data visible

      bf16x8 aF[4], bF[4];
      #pragma unroll
      for (int mf = 0; mf < 4; ++mf)
        aF[mf] = *(const bf16x8*)(lds + laneA + mf * 1024);
      #pragma unroll
      for (int nf = 0; nf < 4; ++nf)
        bF[nf] = *(const bf16x8*)(lds + laneB + nf * 1024);
      #pragma unroll
      for (int mf = 0; mf < 4; ++mf)
        #pragma unroll
        for (int nf = 0; nf < 4; ++nf)
          acc[mf][nf] = __builtin_amdgcn_mfma_f32_16x16x32_bf16(
              aF[mf], bF[nf], acc[mf][nf], 0, 0, 0);
      __syncthreads();  // all reads done before next stage overwrites
    }

    if constexpr (MODE == 0) {
      #pragma unroll
      for (int mf = 0; mf < 4; ++mf)
        #pragma unroll
        for (int nf = 0; nf < 4; ++nf) {
          const int col = n0 + wc * 64 + nf * 16 + (lane & 15);
          #pragma unroll
          for (int r = 0; r < 4; ++r) {
            const int row = m0 + s * 128 + wr * 64 + mf * 16 + ((lane >> 4) << 2) + r;
            Cout[z * cZs + (long)row * ldc + col] = f2bf(acc[mf][nf][r]);
          }
        }
    } else {
      // wslice = (first col of this wave)/64 ; disjoint across waves/blocks
      const int wslice = (n0 + wc * 64) >> 6;
      float* pb = partialOut + (long)wslice * MTOT + m0glob + m0 + s * 128 + wr * 64;
      #pragma unroll
      for (int mf = 0; mf < 4; ++mf)
        #pragma unroll
        for (int r = 0; r < 4; ++r) {
          float sv = 0.f;
          #pragma unroll
          for (int nf = 0; nf < 4; ++nf)
            sv += fast_tanh(acc[mf][nf][r] + b1v[nf]) * w2v[nf];
          sv += __shfl_xor(sv, 1, 64);
          sv += __shfl_xor(sv, 2, 64);
          sv += __shfl_xor(sv, 4, 64);
          sv += __shfl_xor(sv, 8, 64);
          if ((lane & 15) == 0)
            pb[mf * 16 + ((lane >> 4) << 2) + r] = sv;   // plain store, no atomic
        }
    }
  }
}

// ---------------------------------------------------------------------------
// masked softmax over L per (k,b) row; sums 8 col-slices per head first.
// partial: [32][MTOT] f32, wslice ws covers cols ws*64..ws*64+63; head = ws>>3.
__global__ __launch_bounds__(256)
void masked_softmax_kernel(const float* __restrict__ partial,
                           const unsigned char* __restrict__ maskB,
                           const int* __restrict__ maskI,
                           const int* __restrict__ flag,
                           float* __restrict__ out) {
  const int kb = blockIdx.x;          // k*NB + b
  const int k = kb >> 4, b = kb & (NB - 1);
  const long base = (long)kb * LSEQ;
  const bool isByte = (*flag != 0);
  const int tid = threadIdx.x;
  const float* pk = partial + (long)(k * 8) * MTOT + (long)b * LSEQ;

  float x[8];
  float mx = -3.0e38f;
  #pragma unroll
  for (int j = 0; j < 8; ++j) {
    int l = tid + j * 256;
    float v = 0.f;
    #pragma unroll
    for (int ws = 0; ws < 8; ++ws) v += pk[(long)ws * MTOT + l];
    bool msk = isByte ? (maskB[b * LSEQ + l] != 0) : (maskI[b * LSEQ + l] != 0);
    v = msk ? -1e9f : v;
    x[j] = v; mx = fmaxf(mx, v);
  }
  __shared__ float redm[4], reds[4];
  #pragma unroll
  for (int off = 32; off >= 1; off >>= 1) mx = fmaxf(mx, __shfl_xor(mx, off, 64));
  if ((tid & 63) == 0) redm[tid >> 6] = mx;
  __syncthreads();
  mx = fmaxf(fmaxf(redm[0], redm[1]), fmaxf(redm[2], redm[3]));

  float sum = 0.f;
  #pragma unroll
  for (int j = 0; j < 8; ++j) { x[j] = __expf(x[j] - mx); sum += x[j]; }
  #pragma unroll
  for (int off = 32; off >= 1; off >>= 1) sum += __shfl_xor(sum, off, 64);
  if ((tid & 63) == 0) reds[tid >> 6] = sum;
  __syncthreads();
  sum = reds[0] + reds[1] + reds[2] + reds[3];

  float inv = 1.0f / sum;
  #pragma unroll
  for (int j = 0; j < 8; ++j) out[base + tid + j * 256] = x[j] * inv;
}

// ---------------------------------------------------------------------------
extern "C" void kernel_launch(void* const* d_in, const int* in_sizes, int n_in,
                              void* d_out, int out_size, void* d_ws, size_t ws_size,
                              hipStream_t stream) {
  const float* hidden = (const float*)d_in[0];
  const void*  masks  = d_in[1];
  const float* Wp     = (const float*)d_in[2];
  const float* W1     = (const float*)d_in[3];
  const float* b1     = (const float*)d_in[4];
  const float* W2     = (const float*)d_in[5];
  float* out = (float*)d_out;

  // workspace layout (bytes)
  char* ws = (char*)d_ws;
  ushort* W1T      = (ushort*)(ws + 0);                 //  4,194,304  [4][512][1024] bf16
  ushort* WpH      = (ushort*)(ws + 4194304);           //  8,388,608  [4][1024][1024] bf16
  ushort* WfT      = (ushort*)(ws + 12582912);          //  4,194,304  [2048][1024] bf16
  float*  partial  = (float*) (ws + 16777216);          //  4,194,304  [32][32768] f32
  int*    flag     = (int*)   (ws + 20971520);          //        256
  ushort* hiddenBf = (ushort*)(ws + 20971776);          // chunkM*2048 bytes

  const size_t fixedBytes = 20971776;
  size_t avail = (ws_size > fixedBytes) ? (ws_size - fixedBytes) : 0;
  long chunkM = (long)(avail / ((long)HD * 2)) & ~255L;   // multiple of 256 (SREP=2)
  if (chunkM > MTOT) chunkM = MTOT;
  if (chunkM < 256) chunkM = 256;  // requires ws_size >= ~21.5 MB

  hipMemsetAsync(flag, 0, 256, stream);

  detect_mask_kernel<<<8, 256, 0, stream>>>((const unsigned char*)masks, NB * LSEQ, flag);

  // W1T[h][d][j] = bf16(W1[h][j][d])
  dim3 tb(32, 8);
  transpose_cvt_kernel<<<dim3(DD / 32, HD / 32, NK), tb, 0, stream>>>(
      W1, W1T, HD, DD, (long)HD * DD, (long)DD * HD);
  // WpH[h][c][j] = bf16(Wp[c][h*1024+j])
  cvt_wp_heads_kernel<<<4096, 256, 0, stream>>>(Wp, WpH);

  // WfT[h*512+d][c] = sum_j W1T[h][d][j] * WpH[h][c][j]   (= (Wp@W1)^T per head)
  gemm128_kernel<0, 1><<<dim3(DD / 128, HD / 128, NK), 256, 0, stream>>>(
      W1T, HD, (long)DD * HD,
      WpH, HD, (long)HD * HD, HD,
      WfT, HD, (long)DD * HD,
      nullptr, nullptr, nullptr, 0);

  for (long m0 = 0; m0 < MTOT; m0 += chunkM) {
    long cm = chunkM; if (m0 + cm > MTOT) cm = MTOT - m0;
    cvt_f32_bf16_kernel<<<2048, 256, 0, stream>>>(
        hidden + m0 * HD, hiddenBf, cm * HD);
    // partial[col/64][m0+row] = sum over 64 cols of tanh(hidden@WfT^T + b1)*W2
    gemm128_kernel<1, 2><<<dim3(cm / 256, NF2 / 128, 1), 256, 0, stream>>>(
        hiddenBf, HD, 0,
        WfT, HD, 0, HD,
        nullptr, 0, 0,
        b1, W2, partial, (int)m0);
  }

  masked_softmax_kernel<<<NK * NB, 256, 0, stream>>>(
      partial, (const unsigned char*)masks, (const int*)masks, flag, out);
}